// Round 4
// baseline (5510.183 us; speedup 1.0000x reference)
//
#include <hip/hip_runtime.h>
#include <hip/hip_bf16.h>
#include <cstdint>

// Problem dims
#define T_STEPS 128
#define BATCH   32
#define VOCAB   50000
#define EDIM    512
#define HDIM    512
#define GDIM    2048          // 4*H
#define MROWS   4096          // T*B
#define VPAD    50048         // 391 * 128 (padded N for decode GEMM)

typedef short bf16x8 __attribute__((ext_vector_type(8)));
typedef float f32x4  __attribute__((ext_vector_type(4)));
typedef unsigned short us4 __attribute__((ext_vector_type(4)));
typedef unsigned short us8 __attribute__((ext_vector_type(8)));

#define MFMA16(a, b, c) __builtin_amdgcn_mfma_f32_16x16x32_bf16(a, b, c, 0, 0, 0)

__device__ __forceinline__ float sigmoidf_(float x) { return 1.0f / (1.0f + expf(-x)); }

// round-to-nearest-even fp32 -> bf16 bits
__device__ __forceinline__ unsigned short f2bf(float f) {
    unsigned int u = __float_as_uint(f);
    u = (u + 0x7fffu + ((u >> 16) & 1u)) >> 16;
    return (unsigned short)u;
}

// ---------------------------------------------------------------------------
// Prologue kernels
// ---------------------------------------------------------------------------

// dec_W [50000x512] fp32 -> [50048x512] bf16 with zero pad rows
__global__ __launch_bounds__(256) void conv_decw(const float* __restrict__ src,
                                                 unsigned short* __restrict__ dst) {
    long i = ((long)blockIdx.x * 256 + threadIdx.x) * 8;
    if (i >= (long)VPAD * EDIM) return;
    long row = i >> 9;
    us8 v;
    if (row < VOCAB) {
        float4 a = *(const float4*)(src + i);
        float4 b = *(const float4*)(src + i + 4);
        v[0] = f2bf(a.x); v[1] = f2bf(a.y); v[2] = f2bf(a.z); v[3] = f2bf(a.w);
        v[4] = f2bf(b.x); v[5] = f2bf(b.y); v[6] = f2bf(b.z); v[7] = f2bf(b.w);
    } else {
        v = (us8)0;
    }
    *(us8*)(dst + i) = v;
}

// Gate-interleaved pack+convert: dst[n'][k] = bf16(src[(n'&3)*512 + (n'>>2)][k])
__global__ __launch_bounds__(64) void pack_conv(const float* __restrict__ src,
                                                unsigned short* __restrict__ dst) {
    const int n = blockIdx.x;                       // packed row 0..2047
    const int orig = (n & 3) * 512 + (n >> 2);
    const int k = threadIdx.x * 8;
    const float* s = src + (long)orig * 512 + k;
    float4 a = *(const float4*)s;
    float4 b = *(const float4*)(s + 4);
    us8 v;
    v[0] = f2bf(a.x); v[1] = f2bf(a.y); v[2] = f2bf(a.z); v[3] = f2bf(a.w);
    v[4] = f2bf(b.x); v[5] = f2bf(b.y); v[6] = f2bf(b.z); v[7] = f2bf(b.w);
    *(us8*)(dst + (long)n * 512 + k) = v;
}

// packed bias sums
__global__ __launch_bounds__(256) void pack_bias(const float* __restrict__ bih0,
                                                 const float* __restrict__ bhh0,
                                                 const float* __restrict__ bih1,
                                                 const float* __restrict__ bhh1,
                                                 float* __restrict__ b0p,
                                                 float* __restrict__ b1p) {
    const int n = blockIdx.x * 256 + threadIdx.x;   // 0..2047
    const int orig = (n & 3) * 512 + (n >> 2);
    b0p[n] = bih0[orig] + bhh0[orig];
    b1p[n] = bih1[orig] + bhh1[orig];
}

// X[r, :] = bf16(emb[seq[r], :]) for r in [0, T*B)
__global__ __launch_bounds__(256) void gather_x(const int* __restrict__ seq,
                                                const float* __restrict__ emb,
                                                unsigned short* __restrict__ Xbf) {
    long i = ((long)blockIdx.x * 256 + threadIdx.x) * 4;
    if (i >= (long)MROWS * EDIM) return;
    int r   = (int)(i >> 9);
    int col = (int)(i & 511);
    const float* er = emb + (long)seq[r] * EDIM + col;
    float4 e = *(const float4*)er;
    us4 v;
    v[0] = f2bf(e.x); v[1] = f2bf(e.y); v[2] = f2bf(e.z); v[3] = f2bf(e.w);
    *(us4*)(Xbf + i) = v;
}

// c0[b,h] = emb[word[b]] . w2h_W[h] + w2h_b[h]; both layers start with c0, h=0 (bf16)
// Also zeroes the persistent-kernel step counters (must happen EVERY launch).
__global__ __launch_bounds__(256) void init_c0(const int* __restrict__ word,
                                               const float* __restrict__ emb,
                                               const float* __restrict__ w2hW,
                                               const float* __restrict__ w2hb,
                                               float* __restrict__ c0s, float* __restrict__ c1s,
                                               unsigned short* __restrict__ h0A,
                                               unsigned short* __restrict__ h1A,
                                               int* __restrict__ cnt0, int* __restrict__ cnt1) {
    const int idx = blockIdx.x * 256 + threadIdx.x;   // 0..16383
    if (blockIdx.x == 0) {
        if (threadIdx.x < T_STEPS) {
            cnt0[threadIdx.x] = 0;
            cnt1[threadIdx.x] = 0;
        }
    }
    const int b = idx >> 9, hh = idx & 511;
    const float* er = emb + (long)word[b] * EDIM;
    const float* wr = w2hW + (long)hh * EDIM;
    float acc = w2hb[hh];
    #pragma unroll 4
    for (int k = 0; k < EDIM; k += 4) {
        float4 e4 = *(const float4*)(er + k);
        float4 w4 = *(const float4*)(wr + k);
        acc += e4.x * w4.x + e4.y * w4.y + e4.z * w4.z + e4.w * w4.w;
    }
    c0s[idx] = acc;
    c1s[idx] = acc;
    h0A[idx] = 0;
    h1A[idx] = 0;
}

// ---------------------------------------------------------------------------
// MFMA GEMM: C[m,n] = sum_k A[m,k]*Bt[n,k] (+bias1[n] +bias2[n])
// ntstore=1 -> nontemporal C stores (streaming output, don't pollute L2/L3)
// ---------------------------------------------------------------------------
__global__ __launch_bounds__(256) void gemm_bt128(const unsigned short* __restrict__ A,
                                                  const unsigned short* __restrict__ Bt,
                                                  float* __restrict__ C,
                                                  const float* __restrict__ bias1,
                                                  const float* __restrict__ bias2,
                                                  int K, int Nreal, long ldc, int ntn,
                                                  int ntstore) {
    __shared__ __align__(16) unsigned short As[128 * 64];
    __shared__ __align__(16) unsigned short Bs[128 * 64];
    const int tid  = threadIdx.x;
    const long m0  = (long)(blockIdx.x / ntn) * 128;
    const long n0  = (long)(blockIdx.x % ntn) * 128;
    const int lane = tid & 63;
    const int wave = tid >> 6;
    const int wr = wave >> 1, wc = wave & 1;
    const int fr = lane & 15, fq = lane >> 4;

    f32x4 acc[4][4];
    #pragma unroll
    for (int i = 0; i < 4; ++i)
        #pragma unroll
        for (int j = 0; j < 4; ++j) acc[i][j] = (f32x4)0.0f;

    const int srow = tid >> 3;
    const int scol = (tid & 7) * 8;

    for (int kt = 0; kt < K; kt += 64) {
        #pragma unroll
        for (int i = 0; i < 4; ++i) {
            const unsigned short* ga = A  + (m0 + i * 32 + srow) * K + kt + scol;
            const unsigned short* gb = Bt + (n0 + i * 32 + srow) * K + kt + scol;
            __builtin_amdgcn_global_load_lds((const __attribute__((address_space(1))) void*)ga,
                                             (__attribute__((address_space(3))) void*)(As + i * 2048 + tid * 8),
                                             16, 0, 0);
            __builtin_amdgcn_global_load_lds((const __attribute__((address_space(1))) void*)gb,
                                             (__attribute__((address_space(3))) void*)(Bs + i * 2048 + tid * 8),
                                             16, 0, 0);
        }
        asm volatile("s_waitcnt vmcnt(0)" ::: "memory");
        __syncthreads();
        #pragma unroll
        for (int ks = 0; ks < 64; ks += 32) {
            bf16x8 af[4], bfr[4];
            #pragma unroll
            for (int mi = 0; mi < 4; ++mi)
                af[mi] = *(const bf16x8*)&As[(wr * 64 + mi * 16 + fr) * 64 + ks + fq * 8];
            #pragma unroll
            for (int ni = 0; ni < 4; ++ni)
                bfr[ni] = *(const bf16x8*)&Bs[(wc * 64 + ni * 16 + fr) * 64 + ks + fq * 8];
            #pragma unroll
            for (int mi = 0; mi < 4; ++mi)
                #pragma unroll
                for (int ni = 0; ni < 4; ++ni)
                    acc[mi][ni] = MFMA16(af[mi], bfr[ni], acc[mi][ni]);
        }
        __syncthreads();
    }

    #pragma unroll
    for (int mi = 0; mi < 4; ++mi) {
        const long row = m0 + wr * 64 + mi * 16 + fq * 4;
        #pragma unroll
        for (int ni = 0; ni < 4; ++ni) {
            const long col = n0 + wc * 64 + ni * 16 + fr;
            if (col < Nreal) {
                float bs = (bias1 ? bias1[col] : 0.0f) + (bias2 ? bias2[col] : 0.0f);
                #pragma unroll
                for (int r = 0; r < 4; ++r) {
                    float v = acc[mi][ni][r] + bs;
                    float* p = &C[(row + r) * ldc + col];
                    if (ntstore) __builtin_nontemporal_store(v, p);
                    else *p = v;
                }
            }
        }
    }
}

// ---------------------------------------------------------------------------
// Persistent fused LSTM recurrence. ONE launch for all 128 steps x 2 layers.
// Blocks 0..63: layer0 (32 packed cols each, 8 waves x K=64).
// Blocks 64..127: layer1 (waves 0-3: y0@Wih1^T, waves 4-7: h@Whh1^T, K=128 ea).
// Weight fragments + c-state + biases live in REGISTERS across all steps.
// Cross-block sync: per-step arrival counters (device-scope atomics) +
// __threadfence release/acquire. 128 blocks << 256 CUs -> all co-resident.
// ---------------------------------------------------------------------------
__global__ __launch_bounds__(512, 1) void lstm_persist(
        const float* __restrict__ G0,              // [4096][2048] packed (b0p folded)
        const unsigned short* __restrict__ Whh0p,  // [2048][512] packed bf16
        const unsigned short* __restrict__ Wih1p,
        const unsigned short* __restrict__ Whh1p,
        const float* __restrict__ b1p,             // [2048] packed bias sum layer1
        unsigned short* __restrict__ y0bf,         // [T][32][512] bf16
        unsigned short* __restrict__ y1bf,
        unsigned short* __restrict__ h0A, unsigned short* __restrict__ h0B,
        float* __restrict__ c0s,
        unsigned short* __restrict__ h1A, unsigned short* __restrict__ h1B,
        float* __restrict__ c1s,
        float* __restrict__ hf,                    // [2][32][512] fp32 final h
        int* __restrict__ cnt0, int* __restrict__ cnt1) {
    __shared__ float part[8][32][32];
    const int tid = threadIdx.x;
    const int wv = tid >> 6, lane = tid & 63;
    const int fr = lane & 15, fq = lane >> 4;
    const int koff = fq * 8;
    const int bid = blockIdx.x;
    const int pb = tid >> 3, pu = tid & 7;        // pointwise coords (tid<256)

    if (bid < 64) {
        // ================= layer 0 =================
        const int n_base = bid * 32;
        const int kbase  = wv * 64;
        const unsigned short* W0 = Whh0p + (long)(n_base + fr) * 512 + kbase + koff;
        const unsigned short* W1 = W0 + 16 * 512;
        const bf16x8 w00 = *(const bf16x8*)(W0);
        const bf16x8 w01 = *(const bf16x8*)(W0 + 32);
        const bf16x8 w10 = *(const bf16x8*)(W1);
        const bf16x8 w11 = *(const bf16x8*)(W1 + 32);
        const int si = pb * HDIM + bid * 8 + pu;
        float creg = 0.0f;
        if (tid < 256) creg = c0s[si];

        for (int t = 0; t < T_STEPS; ++t) {
            const unsigned short* hin = (t & 1) ? h0B : h0A;
            unsigned short* hout      = (t & 1) ? h0A : h0B;
            if (t > 0) {
                if (tid == 0)
                    while (__hip_atomic_load(cnt0 + t - 1, __ATOMIC_RELAXED,
                                             __HIP_MEMORY_SCOPE_AGENT) < 64)
                        __builtin_amdgcn_s_sleep(1);
                __syncthreads();
                __threadfence();   // acquire: see h0(t-1) written on other XCDs
            }
            const unsigned short* A0 = hin + fr * 512 + kbase + koff;
            const unsigned short* A1 = A0 + 16 * 512;
            const bf16x8 a00 = *(const bf16x8*)(A0);
            const bf16x8 a01 = *(const bf16x8*)(A0 + 32);
            const bf16x8 a10 = *(const bf16x8*)(A1);
            const bf16x8 a11 = *(const bf16x8*)(A1 + 32);
            float4 ad;
            if (tid < 256)
                ad = *(const float4*)(G0 + ((long)t * BATCH + pb) * GDIM + n_base + pu * 4);
            f32x4 acc00 = (f32x4)0.0f, acc01 = (f32x4)0.0f;
            f32x4 acc10 = (f32x4)0.0f, acc11 = (f32x4)0.0f;
            acc00 = MFMA16(a00, w00, acc00); acc00 = MFMA16(a01, w01, acc00);
            acc01 = MFMA16(a00, w10, acc01); acc01 = MFMA16(a01, w11, acc01);
            acc10 = MFMA16(a10, w00, acc10); acc10 = MFMA16(a11, w01, acc10);
            acc11 = MFMA16(a10, w10, acc11); acc11 = MFMA16(a11, w11, acc11);
            #pragma unroll
            for (int r = 0; r < 4; ++r) {
                part[wv][fq * 4 + r][fr]           = acc00[r];
                part[wv][fq * 4 + r][16 + fr]      = acc01[r];
                part[wv][16 + fq * 4 + r][fr]      = acc10[r];
                part[wv][16 + fq * 4 + r][16 + fr] = acc11[r];
            }
            __syncthreads();
            if (tid < 256) {
                float4 g4 = *(const float4*)&part[0][pb][pu * 4];
                #pragma unroll
                for (int w = 1; w < 8; ++w) {
                    float4 p4 = *(const float4*)&part[w][pb][pu * 4];
                    g4.x += p4.x; g4.y += p4.y; g4.z += p4.z; g4.w += p4.w;
                }
                const float vi = g4.x + ad.x, vf = g4.y + ad.y;
                const float vg = g4.z + ad.z, vo = g4.w + ad.w;
                float c = sigmoidf_(vf) * creg + sigmoidf_(vi) * tanhf(vg);
                float h = sigmoidf_(vo) * tanhf(c);
                creg = c;
                const unsigned short hb = f2bf(h);
                hout[si] = hb;
                y0bf[(long)t * (BATCH * HDIM) + si] = hb;
                if (t == T_STEPS - 1) { hf[si] = h; c0s[si] = c; }
            }
            __threadfence();   // release: h0(t), y0(t) visible before flag
            __syncthreads();
            if (tid == 0)
                __hip_atomic_fetch_add(cnt0 + t, 1, __ATOMIC_RELEASE,
                                       __HIP_MEMORY_SCOPE_AGENT);
        }
    } else {
        // ================= layer 1 =================
        const int cg = bid - 64;
        const int n_base = cg * 32;
        const int kbase  = (wv & 3) * 128;
        const unsigned short* Bop = (wv < 4) ? Wih1p : Whh1p;
        const unsigned short* WB0 = Bop + (long)(n_base + fr) * 512 + kbase + koff;
        const unsigned short* WB1 = WB0 + 16 * 512;
        bf16x8 wb0[4], wb1[4];
        #pragma unroll
        for (int kt = 0; kt < 4; ++kt) {
            wb0[kt] = *(const bf16x8*)(WB0 + kt * 32);
            wb1[kt] = *(const bf16x8*)(WB1 + kt * 32);
        }
        const int si = pb * HDIM + cg * 8 + pu;
        float creg = 0.0f;
        float4 bb = make_float4(0.f, 0.f, 0.f, 0.f);
        if (tid < 256) {
            creg = c1s[si];
            bb = *(const float4*)(b1p + n_base + pu * 4);
        }

        for (int t = 0; t < T_STEPS; ++t) {
            const unsigned short* hin = (t & 1) ? h1B : h1A;
            unsigned short* hout      = (t & 1) ? h1A : h1B;
            if (tid == 0) {
                while (__hip_atomic_load(cnt0 + t, __ATOMIC_RELAXED,
                                         __HIP_MEMORY_SCOPE_AGENT) < 64)
                    __builtin_amdgcn_s_sleep(1);
                if (t > 0)
                    while (__hip_atomic_load(cnt1 + t - 1, __ATOMIC_RELAXED,
                                             __HIP_MEMORY_SCOPE_AGENT) < 64)
                        __builtin_amdgcn_s_sleep(1);
            }
            __syncthreads();
            __threadfence();   // acquire: y0(t) and h1(t-1)
            const unsigned short* Aop = (wv < 4) ? (y0bf + (long)t * (BATCH * HDIM)) : hin;
            const unsigned short* A0 = Aop + fr * 512 + kbase + koff;
            const unsigned short* A1 = A0 + 16 * 512;
            bf16x8 a0[4], a1[4];
            #pragma unroll
            for (int kt = 0; kt < 4; ++kt) {
                a0[kt] = *(const bf16x8*)(A0 + kt * 32);
                a1[kt] = *(const bf16x8*)(A1 + kt * 32);
            }
            f32x4 acc00 = (f32x4)0.0f, acc01 = (f32x4)0.0f;
            f32x4 acc10 = (f32x4)0.0f, acc11 = (f32x4)0.0f;
            #pragma unroll
            for (int kt = 0; kt < 4; ++kt) {
                acc00 = MFMA16(a0[kt], wb0[kt], acc00);
                acc01 = MFMA16(a0[kt], wb1[kt], acc01);
                acc10 = MFMA16(a1[kt], wb0[kt], acc10);
                acc11 = MFMA16(a1[kt], wb1[kt], acc11);
            }
            #pragma unroll
            for (int r = 0; r < 4; ++r) {
                part[wv][fq * 4 + r][fr]           = acc00[r];
                part[wv][fq * 4 + r][16 + fr]      = acc01[r];
                part[wv][16 + fq * 4 + r][fr]      = acc10[r];
                part[wv][16 + fq * 4 + r][16 + fr] = acc11[r];
            }
            __syncthreads();
            if (tid < 256) {
                float4 g4 = *(const float4*)&part[0][pb][pu * 4];
                #pragma unroll
                for (int w = 1; w < 8; ++w) {
                    float4 p4 = *(const float4*)&part[w][pb][pu * 4];
                    g4.x += p4.x; g4.y += p4.y; g4.z += p4.z; g4.w += p4.w;
                }
                const float vi = g4.x + bb.x, vf = g4.y + bb.y;
                const float vg = g4.z + bb.z, vo = g4.w + bb.w;
                float c = sigmoidf_(vf) * creg + sigmoidf_(vi) * tanhf(vg);
                float h = sigmoidf_(vo) * tanhf(c);
                creg = c;
                const unsigned short hb = f2bf(h);
                hout[si] = hb;
                y1bf[(long)t * (BATCH * HDIM) + si] = hb;
                if (t == T_STEPS - 1) { hf[BATCH * HDIM + si] = h; c1s[si] = c; }
            }
            __threadfence();
            __syncthreads();
            if (tid == 0)
                __hip_atomic_fetch_add(cnt1 + t, 1, __ATOMIC_RELEASE,
                                       __HIP_MEMORY_SCOPE_AGENT);
        }
    }
}

// d_out tail: [h_f0 | h_f1 | c_f0 | c_f1], 16384 floats each
__global__ __launch_bounds__(256) void finalize_states(const float* __restrict__ hf,
                                                       const float* __restrict__ c0s,
                                                       const float* __restrict__ c1s,
                                                       float* __restrict__ out) {
    const int idx = blockIdx.x * 256 + threadIdx.x;   // 0..65535
    const long base = (long)MROWS * VOCAB;
    float v;
    if (idx < 32768)      v = hf[idx];
    else if (idx < 49152) v = c0s[idx - 32768];
    else                  v = c1s[idx - 49152];
    out[base + idx] = v;
}

// ---------------------------------------------------------------------------
extern "C" void kernel_launch(void* const* d_in, const int* in_sizes, int n_in,
                              void* d_out, int out_size, void* d_ws, size_t ws_size,
                              hipStream_t stream) {
    const int*   word  = (const int*)d_in[0];
    const int*   seq   = (const int*)d_in[1];
    const float* emb   = (const float*)d_in[2];
    const float* w2hW  = (const float*)d_in[3];
    const float* w2hb  = (const float*)d_in[4];
    const float* Wih0  = (const float*)d_in[5];
    const float* Whh0  = (const float*)d_in[6];
    const float* bih0  = (const float*)d_in[7];
    const float* bhh0  = (const float*)d_in[8];
    const float* Wih1  = (const float*)d_in[9];
    const float* Whh1  = (const float*)d_in[10];
    const float* bih1  = (const float*)d_in[11];
    const float* bhh1  = (const float*)d_in[12];
    const float* dec_W = (const float*)d_in[13];
    const float* dec_b = (const float*)d_in[14];
    float* out = (float*)d_out;

    char* ws = (char*)d_ws;
    size_t off = 0;
    float*          G0    = (float*)(ws + off);          off += (size_t)MROWS * GDIM * 4;   // 33.5 MB
    unsigned short* Xbf   = (unsigned short*)(ws + off); off += (size_t)MROWS * EDIM * 2;   //  4.2 MB
    unsigned short* Wih0p = (unsigned short*)(ws + off); off += (size_t)GDIM  * EDIM * 2;   //  2.1 MB
    unsigned short* Whh0p = (unsigned short*)(ws + off); off += (size_t)GDIM  * HDIM * 2;   //  2.1 MB
    unsigned short* Wih1p = (unsigned short*)(ws + off); off += (size_t)GDIM  * HDIM * 2;   //  2.1 MB
    unsigned short* Whh1p = (unsigned short*)(ws + off); off += (size_t)GDIM  * HDIM * 2;   //  2.1 MB
    unsigned short* decWb = (unsigned short*)(ws + off); off += (size_t)VPAD  * EDIM * 2;   // 51.2 MB
    unsigned short* y0bf  = (unsigned short*)(ws + off); off += (size_t)MROWS * HDIM * 2;   //  4.2 MB
    unsigned short* y1bf  = (unsigned short*)(ws + off); off += (size_t)MROWS * HDIM * 2;   //  4.2 MB
    float* b0p = (float*)(ws + off); off += (size_t)GDIM * 4;
    float* b1p = (float*)(ws + off); off += (size_t)GDIM * 4;
    unsigned short* h0A = (unsigned short*)(ws + off); off += (size_t)BATCH * HDIM * 2;
    unsigned short* h0B = (unsigned short*)(ws + off); off += (size_t)BATCH * HDIM * 2;
    unsigned short* h1A = (unsigned short*)(ws + off); off += (size_t)BATCH * HDIM * 2;
    unsigned short* h1B = (unsigned short*)(ws + off); off += (size_t)BATCH * HDIM * 2;
    float* c0s = (float*)(ws + off); off += (size_t)BATCH * HDIM * 4;
    float* c1s = (float*)(ws + off); off += (size_t)BATCH * HDIM * 4;
    float* hf  = (float*)(ws + off); off += (size_t)2 * BATCH * HDIM * 4;
    int*   cnt0 = (int*)(ws + off); off += (size_t)T_STEPS * 4;
    int*   cnt1 = (int*)(ws + off); off += (size_t)T_STEPS * 4;
    // total ~106 MB of d_ws

    // prologue (parallel)
    conv_decw<<<12512, 256, 0, stream>>>(dec_W, decWb);
    pack_conv<<<2048, 64, 0, stream>>>(Wih0, Wih0p);
    pack_conv<<<2048, 64, 0, stream>>>(Whh0, Whh0p);
    pack_conv<<<2048, 64, 0, stream>>>(Wih1, Wih1p);
    pack_conv<<<2048, 64, 0, stream>>>(Whh1, Whh1p);
    pack_bias<<<8, 256, 0, stream>>>(bih0, bhh0, bih1, bhh1, b0p, b1p);
    gather_x<<<2048, 256, 0, stream>>>(seq, emb, Xbf);
    init_c0<<<64, 256, 0, stream>>>(word, emb, w2hW, w2hb, c0s, c1s, h0A, h1A,
                                    cnt0, cnt1);

    // G0 = X @ Wih0p^T + b0p (packed gate order)   [4096 x 2048], K=512
    gemm_bt128<<<32 * 16, 256, 0, stream>>>(Xbf, Wih0p, G0, b0p, nullptr,
                                            512, GDIM, (long)GDIM, 16, 0);

    // whole recurrence: ONE persistent kernel, flag-synced steps
    lstm_persist<<<128, 512, 0, stream>>>(G0, Whh0p, Wih1p, Whh1p, b1p,
                                          y0bf, y1bf, h0A, h0B, c0s,
                                          h1A, h1B, c1s, hf, cnt0, cnt1);

    // decoded = y1 @ dec_W^T + dec_b   [4096 x 50000], K=512  (nontemporal C)
    gemm_bt128<<<32 * 391, 256, 0, stream>>>(y1bf, decWb, out, dec_b, nullptr,
                                             512, VOCAB, (long)VOCAB, 391, 1);

    finalize_states<<<256, 256, 0, stream>>>(hf, c0s, c1s, out);
}

// Round 5
// 1561.318 us; speedup vs baseline: 3.5292x; 3.5292x over previous
//
#include <hip/hip_runtime.h>
#include <hip/hip_bf16.h>
#include <cstdint>

// Problem dims
#define T_STEPS 128
#define BATCH   32
#define VOCAB   50000
#define EDIM    512
#define HDIM    512
#define GDIM    2048          // 4*H
#define MROWS   4096          // T*B
#define VPAD    50048         // 391 * 128 (padded N for decode GEMM)

typedef short bf16x8 __attribute__((ext_vector_type(8)));
typedef float f32x4  __attribute__((ext_vector_type(4)));
typedef unsigned short us4 __attribute__((ext_vector_type(4)));
typedef unsigned short us8 __attribute__((ext_vector_type(8)));

#define MFMA16(a, b, c) __builtin_amdgcn_mfma_f32_16x16x32_bf16(a, b, c, 0, 0, 0)

__device__ __forceinline__ float sigmoidf_(float x) { return 1.0f / (1.0f + expf(-x)); }

// round-to-nearest-even fp32 -> bf16 bits
__device__ __forceinline__ unsigned short f2bf(float f) {
    unsigned int u = __float_as_uint(f);
    u = (u + 0x7fffu + ((u >> 16) & 1u)) >> 16;
    return (unsigned short)u;
}

// ---------------------------------------------------------------------------
// Prologue kernels
// ---------------------------------------------------------------------------

// dec_W [50000x512] fp32 -> [50048x512] bf16 with zero pad rows
__global__ __launch_bounds__(256) void conv_decw(const float* __restrict__ src,
                                                 unsigned short* __restrict__ dst) {
    long i = ((long)blockIdx.x * 256 + threadIdx.x) * 8;
    if (i >= (long)VPAD * EDIM) return;
    long row = i >> 9;
    us8 v;
    if (row < VOCAB) {
        float4 a = *(const float4*)(src + i);
        float4 b = *(const float4*)(src + i + 4);
        v[0] = f2bf(a.x); v[1] = f2bf(a.y); v[2] = f2bf(a.z); v[3] = f2bf(a.w);
        v[4] = f2bf(b.x); v[5] = f2bf(b.y); v[6] = f2bf(b.z); v[7] = f2bf(b.w);
    } else {
        v = (us8)0;
    }
    *(us8*)(dst + i) = v;
}

// Gate-interleaved pack+convert: dst[n'][k] = bf16(src[(n'&3)*512 + (n'>>2)][k])
__global__ __launch_bounds__(64) void pack_conv(const float* __restrict__ src,
                                                unsigned short* __restrict__ dst) {
    const int n = blockIdx.x;                       // packed row 0..2047
    const int orig = (n & 3) * 512 + (n >> 2);
    const int k = threadIdx.x * 8;
    const float* s = src + (long)orig * 512 + k;
    float4 a = *(const float4*)s;
    float4 b = *(const float4*)(s + 4);
    us8 v;
    v[0] = f2bf(a.x); v[1] = f2bf(a.y); v[2] = f2bf(a.z); v[3] = f2bf(a.w);
    v[4] = f2bf(b.x); v[5] = f2bf(b.y); v[6] = f2bf(b.z); v[7] = f2bf(b.w);
    *(us8*)(dst + (long)n * 512 + k) = v;
}

// packed bias sums
__global__ __launch_bounds__(256) void pack_bias(const float* __restrict__ bih0,
                                                 const float* __restrict__ bhh0,
                                                 const float* __restrict__ bih1,
                                                 const float* __restrict__ bhh1,
                                                 float* __restrict__ b0p,
                                                 float* __restrict__ b1p) {
    const int n = blockIdx.x * 256 + threadIdx.x;   // 0..2047
    const int orig = (n & 3) * 512 + (n >> 2);
    b0p[n] = bih0[orig] + bhh0[orig];
    b1p[n] = bih1[orig] + bhh1[orig];
}

// X[r, :] = bf16(emb[seq[r], :]) for r in [0, T*B)
__global__ __launch_bounds__(256) void gather_x(const int* __restrict__ seq,
                                                const float* __restrict__ emb,
                                                unsigned short* __restrict__ Xbf) {
    long i = ((long)blockIdx.x * 256 + threadIdx.x) * 4;
    if (i >= (long)MROWS * EDIM) return;
    int r   = (int)(i >> 9);
    int col = (int)(i & 511);
    const float* er = emb + (long)seq[r] * EDIM + col;
    float4 e = *(const float4*)er;
    us4 v;
    v[0] = f2bf(e.x); v[1] = f2bf(e.y); v[2] = f2bf(e.z); v[3] = f2bf(e.w);
    *(us4*)(Xbf + i) = v;
}

// c0[b,h] = emb[word[b]] . w2h_W[h] + w2h_b[h]; both layers start with c0, h=0 (bf16)
__global__ __launch_bounds__(256) void init_c0(const int* __restrict__ word,
                                               const float* __restrict__ emb,
                                               const float* __restrict__ w2hW,
                                               const float* __restrict__ w2hb,
                                               float* __restrict__ c0s, float* __restrict__ c1s,
                                               unsigned short* __restrict__ h0A,
                                               unsigned short* __restrict__ h1A) {
    const int idx = blockIdx.x * 256 + threadIdx.x;   // 0..16383
    const int b = idx >> 9, hh = idx & 511;
    const float* er = emb + (long)word[b] * EDIM;
    const float* wr = w2hW + (long)hh * EDIM;
    float acc = w2hb[hh];
    #pragma unroll 4
    for (int k = 0; k < EDIM; k += 4) {
        float4 e4 = *(const float4*)(er + k);
        float4 w4 = *(const float4*)(wr + k);
        acc += e4.x * w4.x + e4.y * w4.y + e4.z * w4.z + e4.w * w4.w;
    }
    c0s[idx] = acc;
    c1s[idx] = acc;
    h0A[idx] = 0;
    h1A[idx] = 0;
}

// ---------------------------------------------------------------------------
// MFMA GEMM: C[m,n] = sum_k A[m,k]*Bt[n,k] (+bias1[n] +bias2[n])
// ntstore=1 -> nontemporal C stores. swzdec=1 -> XCD-chunked, B-panel-major
// block mapping (M fixed 4096 = 32 tiles): each XCD walks n-panels
// sequentially so the B panel + whole A stay resident in its private L2.
// ---------------------------------------------------------------------------
__global__ __launch_bounds__(256) void gemm_bt128(const unsigned short* __restrict__ A,
                                                  const unsigned short* __restrict__ Bt,
                                                  float* __restrict__ C,
                                                  const float* __restrict__ bias1,
                                                  const float* __restrict__ bias2,
                                                  int K, int Nreal, long ldc, int ntn,
                                                  int ntstore, int swzdec) {
    __shared__ __align__(16) unsigned short As[128 * 64];
    __shared__ __align__(16) unsigned short Bs[128 * 64];
    const int tid  = threadIdx.x;
    long m0, n0;
    if (swzdec) {
        const int cpx = gridDim.x >> 3;                   // blocks per XCD chunk
        const int s = (blockIdx.x & 7) * cpx + (blockIdx.x >> 3);
        m0 = (long)(s & 31) * 128;                        // 32 M-tiles
        n0 = (long)(s >> 5) * 128;
    } else {
        m0 = (long)(blockIdx.x / ntn) * 128;
        n0 = (long)(blockIdx.x % ntn) * 128;
    }
    const int lane = tid & 63;
    const int wave = tid >> 6;
    const int wr = wave >> 1, wc = wave & 1;
    const int fr = lane & 15, fq = lane >> 4;

    f32x4 acc[4][4];
    #pragma unroll
    for (int i = 0; i < 4; ++i)
        #pragma unroll
        for (int j = 0; j < 4; ++j) acc[i][j] = (f32x4)0.0f;

    const int srow = tid >> 3;
    const int scol = (tid & 7) * 8;

    for (int kt = 0; kt < K; kt += 64) {
        #pragma unroll
        for (int i = 0; i < 4; ++i) {
            const unsigned short* ga = A  + (m0 + i * 32 + srow) * K + kt + scol;
            const unsigned short* gb = Bt + (n0 + i * 32 + srow) * K + kt + scol;
            __builtin_amdgcn_global_load_lds((const __attribute__((address_space(1))) void*)ga,
                                             (__attribute__((address_space(3))) void*)(As + i * 2048 + tid * 8),
                                             16, 0, 0);
            __builtin_amdgcn_global_load_lds((const __attribute__((address_space(1))) void*)gb,
                                             (__attribute__((address_space(3))) void*)(Bs + i * 2048 + tid * 8),
                                             16, 0, 0);
        }
        asm volatile("s_waitcnt vmcnt(0)" ::: "memory");
        __syncthreads();
        #pragma unroll
        for (int ks = 0; ks < 64; ks += 32) {
            bf16x8 af[4], bfr[4];
            #pragma unroll
            for (int mi = 0; mi < 4; ++mi)
                af[mi] = *(const bf16x8*)&As[(wr * 64 + mi * 16 + fr) * 64 + ks + fq * 8];
            #pragma unroll
            for (int ni = 0; ni < 4; ++ni)
                bfr[ni] = *(const bf16x8*)&Bs[(wc * 64 + ni * 16 + fr) * 64 + ks + fq * 8];
            #pragma unroll
            for (int mi = 0; mi < 4; ++mi)
                #pragma unroll
                for (int ni = 0; ni < 4; ++ni)
                    acc[mi][ni] = MFMA16(af[mi], bfr[ni], acc[mi][ni]);
        }
        __syncthreads();
    }

    #pragma unroll
    for (int mi = 0; mi < 4; ++mi) {
        const long row = m0 + wr * 64 + mi * 16 + fq * 4;
        #pragma unroll
        for (int ni = 0; ni < 4; ++ni) {
            const long col = n0 + wc * 64 + ni * 16 + fr;
            if (col < Nreal) {
                float bs = (bias1 ? bias1[col] : 0.0f) + (bias2 ? bias2[col] : 0.0f);
                #pragma unroll
                for (int r = 0; r < 4; ++r) {
                    float v = acc[mi][ni][r] + bs;
                    float* p = &C[(row + r) * ldc + col];
                    if (ntstore) __builtin_nontemporal_store(v, p);
                    else *p = v;
                }
            }
        }
    }
}

// ---------------------------------------------------------------------------
// LSTM step, wave-level K-split (skewed): blocks 0..63 layer0 step t (32 packed
// cols each, 8 waves x K=64), blocks 64..127 layer1 step t-1 (32 cols, waves
// 0-3: y0@Wih1^T K=128 chunks, waves 4-7: h@Whh1^T K=128 chunks).
// G0/bias/c prefetched into registers at kernel entry (overlap with MFMA path);
// kernel-launch boundary IS the cross-block barrier (R3 showed flag-sync at
// agent scope costs ~39us/step vs ~7us/step for launches).
// ---------------------------------------------------------------------------
__global__ __launch_bounds__(512) void lstm_step2(
        const float* __restrict__ G0,              // [4096][2048] packed (b0p folded)
        const unsigned short* __restrict__ Whh0p,  // [2048][512] packed bf16
        const unsigned short* __restrict__ Wih1p,
        const unsigned short* __restrict__ Whh1p,
        const float* __restrict__ b1p,             // [2048] packed bias sum layer1
        unsigned short* __restrict__ y0bf,         // [T][32][512] bf16
        unsigned short* __restrict__ y1bf,
        unsigned short* __restrict__ h0A, unsigned short* __restrict__ h0B,
        float* __restrict__ c0s,
        unsigned short* __restrict__ h1A, unsigned short* __restrict__ h1B,
        float* __restrict__ c1s,
        float* __restrict__ hf,                    // [2][32][512] fp32 final h
        int t) {
    __shared__ float part[8][32][32];              // 32 KB partial tiles
    int bid = blockIdx.x;
    const int tid  = threadIdx.x;
    const int wv   = tid >> 6, lane = tid & 63;
    const int fr   = lane & 15, fq = lane >> 4;

    int layer, tt, cg;
    if (bid < 64) { layer = 0; tt = t;     if (tt >= T_STEPS) return; cg = bid; }
    else          { layer = 1; tt = t - 1; if (tt < 0) return;       cg = bid - 64; }

    const unsigned short* hin;
    unsigned short* hout;
    float* cs;
    if (layer == 0) { hin = (tt & 1) ? h0B : h0A; hout = (tt & 1) ? h0A : h0B; cs = c0s; }
    else            { hin = (tt & 1) ? h1B : h1A; hout = (tt & 1) ? h1A : h1B; cs = c1s; }

    const int n_base = cg * 32;

    // ---- early prefetch of pointwise operands (hide latency under MFMA) ----
    const int pb = tid >> 3, pu = tid & 7;         // pointwise coords (tid<256)
    const int si = pb * HDIM + cg * 8 + pu;
    float creg = 0.0f;
    float4 ad = make_float4(0.f, 0.f, 0.f, 0.f);
    if (tid < 256) {
        creg = cs[si];
        if (layer == 0) ad = *(const float4*)(G0 + ((long)tt * BATCH + pb) * GDIM + n_base + pu * 4);
        else            ad = *(const float4*)(b1p + n_base + pu * 4);
    }

    f32x4 acc[2][2];
    acc[0][0] = (f32x4)0.0f; acc[0][1] = (f32x4)0.0f;
    acc[1][0] = (f32x4)0.0f; acc[1][1] = (f32x4)0.0f;

    if (layer == 0) {
        // waves 0..7, K chunk = 64 each, fully unrolled
        const int kbase = wv * 64;
        const unsigned short* A0 = hin + fr * 512 + kbase + fq * 8;
        const unsigned short* A1 = A0 + 16 * 512;
        const unsigned short* B0 = Whh0p + (long)(n_base + fr) * 512 + kbase + fq * 8;
        const unsigned short* B1 = B0 + 16 * 512;
        #pragma unroll
        for (int i = 0; i < 2; ++i) {
            bf16x8 a0 = *(const bf16x8*)(A0 + i * 32);
            bf16x8 a1 = *(const bf16x8*)(A1 + i * 32);
            bf16x8 b0 = *(const bf16x8*)(B0 + i * 32);
            bf16x8 b1 = *(const bf16x8*)(B1 + i * 32);
            acc[0][0] = MFMA16(a0, b0, acc[0][0]);
            acc[0][1] = MFMA16(a0, b1, acc[0][1]);
            acc[1][0] = MFMA16(a1, b0, acc[1][0]);
            acc[1][1] = MFMA16(a1, b1, acc[1][1]);
        }
    } else {
        // waves 0..3: y0[tt] @ Wih1^T ; waves 4..7: h1 @ Whh1^T ; K chunk = 128
        const unsigned short* Aop = (wv < 4) ? (y0bf + (long)tt * (BATCH * HDIM)) : hin;
        const unsigned short* Bop = (wv < 4) ? Wih1p : Whh1p;
        const int kbase = (wv & 3) * 128;
        const unsigned short* A0 = Aop + fr * 512 + kbase + fq * 8;
        const unsigned short* A1 = A0 + 16 * 512;
        const unsigned short* B0 = Bop + (long)(n_base + fr) * 512 + kbase + fq * 8;
        const unsigned short* B1 = B0 + 16 * 512;
        #pragma unroll
        for (int i = 0; i < 4; ++i) {
            bf16x8 a0 = *(const bf16x8*)(A0 + i * 32);
            bf16x8 a1 = *(const bf16x8*)(A1 + i * 32);
            bf16x8 b0 = *(const bf16x8*)(B0 + i * 32);
            bf16x8 b1 = *(const bf16x8*)(B1 + i * 32);
            acc[0][0] = MFMA16(a0, b0, acc[0][0]);
            acc[0][1] = MFMA16(a0, b1, acc[0][1]);
            acc[1][0] = MFMA16(a1, b0, acc[1][0]);
            acc[1][1] = MFMA16(a1, b1, acc[1][1]);
        }
    }

    // partial tiles -> LDS
    #pragma unroll
    for (int mi = 0; mi < 2; ++mi)
        #pragma unroll
        for (int ni = 0; ni < 2; ++ni)
            #pragma unroll
            for (int r = 0; r < 4; ++r)
                part[wv][mi * 16 + fq * 4 + r][ni * 16 + fr] = acc[mi][ni][r];
    __syncthreads();

    // reduce + pointwise: threads 0..255, one (batch, unit) each
    if (tid < 256) {
        float4 g4 = *(const float4*)&part[0][pb][pu * 4];
        #pragma unroll
        for (int w = 1; w < 8; ++w) {
            float4 p4 = *(const float4*)&part[w][pb][pu * 4];
            g4.x += p4.x; g4.y += p4.y; g4.z += p4.z; g4.w += p4.w;
        }
        const float vi = g4.x + ad.x, vf = g4.y + ad.y;
        const float vg = g4.z + ad.z, vo = g4.w + ad.w;
        float c = sigmoidf_(vf) * creg + sigmoidf_(vi) * tanhf(vg);
        float h = sigmoidf_(vo) * tanhf(c);
        cs[si] = c;
        const unsigned short hb = f2bf(h);
        hout[si] = hb;
        if (layer == 0) y0bf[(long)tt * (BATCH * HDIM) + si] = hb;
        else            y1bf[(long)tt * (BATCH * HDIM) + si] = hb;
        if (tt == T_STEPS - 1) hf[layer * (BATCH * HDIM) + si] = h;
    }
}

// d_out tail: [h_f0 | h_f1 | c_f0 | c_f1], 16384 floats each
__global__ __launch_bounds__(256) void finalize_states(const float* __restrict__ hf,
                                                       const float* __restrict__ c0s,
                                                       const float* __restrict__ c1s,
                                                       float* __restrict__ out) {
    const int idx = blockIdx.x * 256 + threadIdx.x;   // 0..65535
    const long base = (long)MROWS * VOCAB;
    float v;
    if (idx < 32768)      v = hf[idx];
    else if (idx < 49152) v = c0s[idx - 32768];
    else                  v = c1s[idx - 49152];
    out[base + idx] = v;
}

// ---------------------------------------------------------------------------
extern "C" void kernel_launch(void* const* d_in, const int* in_sizes, int n_in,
                              void* d_out, int out_size, void* d_ws, size_t ws_size,
                              hipStream_t stream) {
    const int*   word  = (const int*)d_in[0];
    const int*   seq   = (const int*)d_in[1];
    const float* emb   = (const float*)d_in[2];
    const float* w2hW  = (const float*)d_in[3];
    const float* w2hb  = (const float*)d_in[4];
    const float* Wih0  = (const float*)d_in[5];
    const float* Whh0  = (const float*)d_in[6];
    const float* bih0  = (const float*)d_in[7];
    const float* bhh0  = (const float*)d_in[8];
    const float* Wih1  = (const float*)d_in[9];
    const float* Whh1  = (const float*)d_in[10];
    const float* bih1  = (const float*)d_in[11];
    const float* bhh1  = (const float*)d_in[12];
    const float* dec_W = (const float*)d_in[13];
    const float* dec_b = (const float*)d_in[14];
    float* out = (float*)d_out;

    char* ws = (char*)d_ws;
    size_t off = 0;
    float*          G0    = (float*)(ws + off);          off += (size_t)MROWS * GDIM * 4;   // 33.5 MB
    unsigned short* Xbf   = (unsigned short*)(ws + off); off += (size_t)MROWS * EDIM * 2;   //  4.2 MB
    unsigned short* Wih0p = (unsigned short*)(ws + off); off += (size_t)GDIM  * EDIM * 2;   //  2.1 MB
    unsigned short* Whh0p = (unsigned short*)(ws + off); off += (size_t)GDIM  * HDIM * 2;   //  2.1 MB
    unsigned short* Wih1p = (unsigned short*)(ws + off); off += (size_t)GDIM  * HDIM * 2;   //  2.1 MB
    unsigned short* Whh1p = (unsigned short*)(ws + off); off += (size_t)GDIM  * HDIM * 2;   //  2.1 MB
    unsigned short* decWb = (unsigned short*)(ws + off); off += (size_t)VPAD  * EDIM * 2;   // 51.2 MB
    unsigned short* y0bf  = (unsigned short*)(ws + off); off += (size_t)MROWS * HDIM * 2;   //  4.2 MB
    unsigned short* y1bf  = (unsigned short*)(ws + off); off += (size_t)MROWS * HDIM * 2;   //  4.2 MB
    float* b0p = (float*)(ws + off); off += (size_t)GDIM * 4;
    float* b1p = (float*)(ws + off); off += (size_t)GDIM * 4;
    unsigned short* h0A = (unsigned short*)(ws + off); off += (size_t)BATCH * HDIM * 2;
    unsigned short* h0B = (unsigned short*)(ws + off); off += (size_t)BATCH * HDIM * 2;
    unsigned short* h1A = (unsigned short*)(ws + off); off += (size_t)BATCH * HDIM * 2;
    unsigned short* h1B = (unsigned short*)(ws + off); off += (size_t)BATCH * HDIM * 2;
    float* c0s = (float*)(ws + off); off += (size_t)BATCH * HDIM * 4;
    float* c1s = (float*)(ws + off); off += (size_t)BATCH * HDIM * 4;
    float* hf  = (float*)(ws + off); off += (size_t)2 * BATCH * HDIM * 4;
    // total ~106 MB of d_ws

    // prologue (parallel)
    conv_decw<<<12512, 256, 0, stream>>>(dec_W, decWb);
    pack_conv<<<2048, 64, 0, stream>>>(Wih0, Wih0p);
    pack_conv<<<2048, 64, 0, stream>>>(Whh0, Whh0p);
    pack_conv<<<2048, 64, 0, stream>>>(Wih1, Wih1p);
    pack_conv<<<2048, 64, 0, stream>>>(Whh1, Whh1p);
    pack_bias<<<8, 256, 0, stream>>>(bih0, bhh0, bih1, bhh1, b0p, b1p);
    gather_x<<<2048, 256, 0, stream>>>(seq, emb, Xbf);
    init_c0<<<64, 256, 0, stream>>>(word, emb, w2hW, w2hb, c0s, c1s, h0A, h1A);

    // G0 = X @ Wih0p^T + b0p (packed gate order)   [4096 x 2048], K=512
    gemm_bt128<<<32 * 16, 256, 0, stream>>>(Xbf, Wih0p, G0, b0p, nullptr,
                                            512, GDIM, (long)GDIM, 16, 0, 0);

    // skewed recurrence: layer0 step t || layer1 step t-1
    for (int t = 0; t <= T_STEPS; ++t)
        lstm_step2<<<128, 512, 0, stream>>>(G0, Whh0p, Wih1p, Whh1p, b1p,
                                            y0bf, y1bf, h0A, h0B, c0s,
                                            h1A, h1B, c1s, hf, t);

    // decoded = y1 @ dec_W^T + dec_b   [4096 x 50000], K=512
    // nontemporal C stores + XCD-chunked B-panel-major swizzle
    gemm_bt128<<<32 * 391, 256, 0, stream>>>(y1bf, decWb, out, dec_b, nullptr,
                                             512, VOCAB, (long)VOCAB, 391, 1, 1);

    finalize_states<<<256, 256, 0, stream>>>(hf, c0s, c1s, out);
}

// Round 6
// 1509.199 us; speedup vs baseline: 3.6511x; 1.0345x over previous
//
#include <hip/hip_runtime.h>
#include <hip/hip_bf16.h>
#include <cstdint>

// Problem dims
#define T_STEPS 128
#define BATCH   32
#define VOCAB   50000
#define EDIM    512
#define HDIM    512
#define GDIM    2048          // 4*H
#define MROWS   4096          // T*B
#define VPAD    50048         // 391 * 128 (padded N for decode GEMM)

typedef short bf16x8 __attribute__((ext_vector_type(8)));
typedef float f32x4  __attribute__((ext_vector_type(4)));
typedef unsigned short us4 __attribute__((ext_vector_type(4)));
typedef unsigned short us8 __attribute__((ext_vector_type(8)));

#define MFMA16(a, b, c) __builtin_amdgcn_mfma_f32_16x16x32_bf16(a, b, c, 0, 0, 0)

// fast activations: __expf -> v_exp_f32 (native); division keeps full accuracy
__device__ __forceinline__ float fsigmoid(float x) {
    return 1.0f / (1.0f + __expf(-x));
}
__device__ __forceinline__ float ftanh(float x) {
    // tanh(x) = 1 - 2/(e^{2x}+1); saturates correctly for |x| large
    return 1.0f - 2.0f / (1.0f + __expf(2.0f * x));
}

// round-to-nearest-even fp32 -> bf16 bits
__device__ __forceinline__ unsigned short f2bf(float f) {
    unsigned int u = __float_as_uint(f);
    u = (u + 0x7fffu + ((u >> 16) & 1u)) >> 16;
    return (unsigned short)u;
}

// ---------------------------------------------------------------------------
// Prologue kernels
// ---------------------------------------------------------------------------

// dec_W [50000x512] fp32 -> [50048x512] bf16 with zero pad rows
__global__ __launch_bounds__(256) void conv_decw(const float* __restrict__ src,
                                                 unsigned short* __restrict__ dst) {
    long i = ((long)blockIdx.x * 256 + threadIdx.x) * 8;
    if (i >= (long)VPAD * EDIM) return;
    long row = i >> 9;
    us8 v;
    if (row < VOCAB) {
        float4 a = *(const float4*)(src + i);
        float4 b = *(const float4*)(src + i + 4);
        v[0] = f2bf(a.x); v[1] = f2bf(a.y); v[2] = f2bf(a.z); v[3] = f2bf(a.w);
        v[4] = f2bf(b.x); v[5] = f2bf(b.y); v[6] = f2bf(b.z); v[7] = f2bf(b.w);
    } else {
        v = (us8)0;
    }
    *(us8*)(dst + i) = v;
}

// Gate-interleaved pack+convert: dst[n'][k] = bf16(src[(n'&3)*512 + (n'>>2)][k])
__global__ __launch_bounds__(64) void pack_conv(const float* __restrict__ src,
                                                unsigned short* __restrict__ dst) {
    const int n = blockIdx.x;                       // packed row 0..2047
    const int orig = (n & 3) * 512 + (n >> 2);
    const int k = threadIdx.x * 8;
    const float* s = src + (long)orig * 512 + k;
    float4 a = *(const float4*)s;
    float4 b = *(const float4*)(s + 4);
    us8 v;
    v[0] = f2bf(a.x); v[1] = f2bf(a.y); v[2] = f2bf(a.z); v[3] = f2bf(a.w);
    v[4] = f2bf(b.x); v[5] = f2bf(b.y); v[6] = f2bf(b.z); v[7] = f2bf(b.w);
    *(us8*)(dst + (long)n * 512 + k) = v;
}

// packed bias sums
__global__ __launch_bounds__(256) void pack_bias(const float* __restrict__ bih0,
                                                 const float* __restrict__ bhh0,
                                                 const float* __restrict__ bih1,
                                                 const float* __restrict__ bhh1,
                                                 float* __restrict__ b0p,
                                                 float* __restrict__ b1p) {
    const int n = blockIdx.x * 256 + threadIdx.x;   // 0..2047
    const int orig = (n & 3) * 512 + (n >> 2);
    b0p[n] = bih0[orig] + bhh0[orig];
    b1p[n] = bih1[orig] + bhh1[orig];
}

// X[r, :] = bf16(emb[seq[r], :]) for r in [0, T*B)
__global__ __launch_bounds__(256) void gather_x(const int* __restrict__ seq,
                                                const float* __restrict__ emb,
                                                unsigned short* __restrict__ Xbf) {
    long i = ((long)blockIdx.x * 256 + threadIdx.x) * 4;
    if (i >= (long)MROWS * EDIM) return;
    int r   = (int)(i >> 9);
    int col = (int)(i & 511);
    const float* er = emb + (long)seq[r] * EDIM + col;
    float4 e = *(const float4*)er;
    us4 v;
    v[0] = f2bf(e.x); v[1] = f2bf(e.y); v[2] = f2bf(e.z); v[3] = f2bf(e.w);
    *(us4*)(Xbf + i) = v;
}

// c0[b,h] = emb[word[b]] . w2h_W[h] + w2h_b[h]; both layers start with c0, h=0 (bf16)
__global__ __launch_bounds__(256) void init_c0(const int* __restrict__ word,
                                               const float* __restrict__ emb,
                                               const float* __restrict__ w2hW,
                                               const float* __restrict__ w2hb,
                                               float* __restrict__ c0s, float* __restrict__ c1s,
                                               unsigned short* __restrict__ h0A,
                                               unsigned short* __restrict__ h1A) {
    const int idx = blockIdx.x * 256 + threadIdx.x;   // 0..16383
    const int b = idx >> 9, hh = idx & 511;
    const float* er = emb + (long)word[b] * EDIM;
    const float* wr = w2hW + (long)hh * EDIM;
    float acc = w2hb[hh];
    #pragma unroll 4
    for (int k = 0; k < EDIM; k += 4) {
        float4 e4 = *(const float4*)(er + k);
        float4 w4 = *(const float4*)(wr + k);
        acc += e4.x * w4.x + e4.y * w4.y + e4.z * w4.z + e4.w * w4.w;
    }
    c0s[idx] = acc;
    c1s[idx] = acc;
    h0A[idx] = 0;
    h1A[idx] = 0;
}

// ---------------------------------------------------------------------------
// MFMA GEMM: C[m,n] = sum_k A[m,k]*Bt[n,k] (+bias1[n] +bias2[n])
// mode bit0: nontemporal C stores (streaming output).
// mode bit1: n-major block order (m-tile fastest, M fixed at 32 tiles):
//   all co-resident blocks share the SAME ~40 n-panels while A (32MB) stays
//   L3-resident across its 391-fold reuse; B is streamed exactly once.
// ---------------------------------------------------------------------------
__global__ __launch_bounds__(256) void gemm_bt128(const unsigned short* __restrict__ A,
                                                  const unsigned short* __restrict__ Bt,
                                                  float* __restrict__ C,
                                                  const float* __restrict__ bias1,
                                                  const float* __restrict__ bias2,
                                                  int K, int Nreal, long ldc, int ntn,
                                                  int mode) {
    __shared__ __align__(16) unsigned short As[128 * 64];
    __shared__ __align__(16) unsigned short Bs[128 * 64];
    const int tid  = threadIdx.x;
    long m0, n0;
    if (mode & 2) {
        m0 = (long)(blockIdx.x & 31) * 128;   // m fastest
        n0 = (long)(blockIdx.x >> 5) * 128;
    } else {
        m0 = (long)(blockIdx.x / ntn) * 128;
        n0 = (long)(blockIdx.x % ntn) * 128;
    }
    const int lane = tid & 63;
    const int wave = tid >> 6;
    const int wr = wave >> 1, wc = wave & 1;
    const int fr = lane & 15, fq = lane >> 4;

    f32x4 acc[4][4];
    #pragma unroll
    for (int i = 0; i < 4; ++i)
        #pragma unroll
        for (int j = 0; j < 4; ++j) acc[i][j] = (f32x4)0.0f;

    const int srow = tid >> 3;
    const int scol = (tid & 7) * 8;

    for (int kt = 0; kt < K; kt += 64) {
        #pragma unroll
        for (int i = 0; i < 4; ++i) {
            const unsigned short* ga = A  + (m0 + i * 32 + srow) * K + kt + scol;
            const unsigned short* gb = Bt + (n0 + i * 32 + srow) * K + kt + scol;
            __builtin_amdgcn_global_load_lds((const __attribute__((address_space(1))) void*)ga,
                                             (__attribute__((address_space(3))) void*)(As + i * 2048 + tid * 8),
                                             16, 0, 0);
            __builtin_amdgcn_global_load_lds((const __attribute__((address_space(1))) void*)gb,
                                             (__attribute__((address_space(3))) void*)(Bs + i * 2048 + tid * 8),
                                             16, 0, 0);
        }
        asm volatile("s_waitcnt vmcnt(0)" ::: "memory");
        __syncthreads();
        #pragma unroll
        for (int ks = 0; ks < 64; ks += 32) {
            bf16x8 af[4], bfr[4];
            #pragma unroll
            for (int mi = 0; mi < 4; ++mi)
                af[mi] = *(const bf16x8*)&As[(wr * 64 + mi * 16 + fr) * 64 + ks + fq * 8];
            #pragma unroll
            for (int ni = 0; ni < 4; ++ni)
                bfr[ni] = *(const bf16x8*)&Bs[(wc * 64 + ni * 16 + fr) * 64 + ks + fq * 8];
            #pragma unroll
            for (int mi = 0; mi < 4; ++mi)
                #pragma unroll
                for (int ni = 0; ni < 4; ++ni)
                    acc[mi][ni] = MFMA16(af[mi], bfr[ni], acc[mi][ni]);
        }
        __syncthreads();
    }

    #pragma unroll
    for (int mi = 0; mi < 4; ++mi) {
        const long row = m0 + wr * 64 + mi * 16 + fq * 4;
        #pragma unroll
        for (int ni = 0; ni < 4; ++ni) {
            const long col = n0 + wc * 64 + ni * 16 + fr;
            if (col < Nreal) {
                float bs = (bias1 ? bias1[col] : 0.0f) + (bias2 ? bias2[col] : 0.0f);
                #pragma unroll
                for (int r = 0; r < 4; ++r) {
                    float v = acc[mi][ni][r] + bs;
                    float* p = &C[(row + r) * ldc + col];
                    if (mode & 1) __builtin_nontemporal_store(v, p);
                    else *p = v;
                }
            }
        }
    }
}

// ---------------------------------------------------------------------------
// LSTM step, wave-level K-split (skewed): blocks 0..63 layer0 step t (32 packed
// cols each, 8 waves x K=64), blocks 64..127 layer1 step t-1 (32 cols, waves
// 0-3: y0@Wih1^T K=128 chunks, waves 4-7: h@Whh1^T K=128 chunks).
// G0/bias/c prefetched into registers at kernel entry (overlap with MFMA path);
// kernel-launch boundary IS the cross-block barrier (R3: agent-scope flag sync
// costs ~39us/step vs ~7us/step for launches).
// ---------------------------------------------------------------------------
__global__ __launch_bounds__(512) void lstm_step2(
        const float* __restrict__ G0,              // [4096][2048] packed (b0p folded)
        const unsigned short* __restrict__ Whh0p,  // [2048][512] packed bf16
        const unsigned short* __restrict__ Wih1p,
        const unsigned short* __restrict__ Whh1p,
        const float* __restrict__ b1p,             // [2048] packed bias sum layer1
        unsigned short* __restrict__ y0bf,         // [T][32][512] bf16
        unsigned short* __restrict__ y1bf,
        unsigned short* __restrict__ h0A, unsigned short* __restrict__ h0B,
        float* __restrict__ c0s,
        unsigned short* __restrict__ h1A, unsigned short* __restrict__ h1B,
        float* __restrict__ c1s,
        float* __restrict__ hf,                    // [2][32][512] fp32 final h
        int t) {
    __shared__ float part[8][32][32];              // 32 KB partial tiles
    int bid = blockIdx.x;
    const int tid  = threadIdx.x;
    const int wv   = tid >> 6, lane = tid & 63;
    const int fr   = lane & 15, fq = lane >> 4;

    int layer, tt, cg;
    if (bid < 64) { layer = 0; tt = t;     if (tt >= T_STEPS) return; cg = bid; }
    else          { layer = 1; tt = t - 1; if (tt < 0) return;       cg = bid - 64; }

    const unsigned short* hin;
    unsigned short* hout;
    float* cs;
    if (layer == 0) { hin = (tt & 1) ? h0B : h0A; hout = (tt & 1) ? h0A : h0B; cs = c0s; }
    else            { hin = (tt & 1) ? h1B : h1A; hout = (tt & 1) ? h1A : h1B; cs = c1s; }

    const int n_base = cg * 32;

    // ---- early prefetch of pointwise operands (hide latency under MFMA) ----
    const int pb = tid >> 3, pu = tid & 7;         // pointwise coords (tid<256)
    const int si = pb * HDIM + cg * 8 + pu;
    float creg = 0.0f;
    float4 ad = make_float4(0.f, 0.f, 0.f, 0.f);
    if (tid < 256) {
        creg = cs[si];
        if (layer == 0) ad = *(const float4*)(G0 + ((long)tt * BATCH + pb) * GDIM + n_base + pu * 4);
        else            ad = *(const float4*)(b1p + n_base + pu * 4);
    }

    f32x4 acc[2][2];
    acc[0][0] = (f32x4)0.0f; acc[0][1] = (f32x4)0.0f;
    acc[1][0] = (f32x4)0.0f; acc[1][1] = (f32x4)0.0f;

    if (layer == 0) {
        // waves 0..7, K chunk = 64 each, fully unrolled
        const int kbase = wv * 64;
        const unsigned short* A0 = hin + fr * 512 + kbase + fq * 8;
        const unsigned short* A1 = A0 + 16 * 512;
        const unsigned short* B0 = Whh0p + (long)(n_base + fr) * 512 + kbase + fq * 8;
        const unsigned short* B1 = B0 + 16 * 512;
        #pragma unroll
        for (int i = 0; i < 2; ++i) {
            bf16x8 a0 = *(const bf16x8*)(A0 + i * 32);
            bf16x8 a1 = *(const bf16x8*)(A1 + i * 32);
            bf16x8 b0 = *(const bf16x8*)(B0 + i * 32);
            bf16x8 b1 = *(const bf16x8*)(B1 + i * 32);
            acc[0][0] = MFMA16(a0, b0, acc[0][0]);
            acc[0][1] = MFMA16(a0, b1, acc[0][1]);
            acc[1][0] = MFMA16(a1, b0, acc[1][0]);
            acc[1][1] = MFMA16(a1, b1, acc[1][1]);
        }
    } else {
        // waves 0..3: y0[tt] @ Wih1^T ; waves 4..7: h1 @ Whh1^T ; K chunk = 128
        const unsigned short* Aop = (wv < 4) ? (y0bf + (long)tt * (BATCH * HDIM)) : hin;
        const unsigned short* Bop = (wv < 4) ? Wih1p : Whh1p;
        const int kbase = (wv & 3) * 128;
        const unsigned short* A0 = Aop + fr * 512 + kbase + fq * 8;
        const unsigned short* A1 = A0 + 16 * 512;
        const unsigned short* B0 = Bop + (long)(n_base + fr) * 512 + kbase + fq * 8;
        const unsigned short* B1 = B0 + 16 * 512;
        #pragma unroll
        for (int i = 0; i < 4; ++i) {
            bf16x8 a0 = *(const bf16x8*)(A0 + i * 32);
            bf16x8 a1 = *(const bf16x8*)(A1 + i * 32);
            bf16x8 b0 = *(const bf16x8*)(B0 + i * 32);
            bf16x8 b1 = *(const bf16x8*)(B1 + i * 32);
            acc[0][0] = MFMA16(a0, b0, acc[0][0]);
            acc[0][1] = MFMA16(a0, b1, acc[0][1]);
            acc[1][0] = MFMA16(a1, b0, acc[1][0]);
            acc[1][1] = MFMA16(a1, b1, acc[1][1]);
        }
    }

    // partial tiles -> LDS
    #pragma unroll
    for (int mi = 0; mi < 2; ++mi)
        #pragma unroll
        for (int ni = 0; ni < 2; ++ni)
            #pragma unroll
            for (int r = 0; r < 4; ++r)
                part[wv][mi * 16 + fq * 4 + r][ni * 16 + fr] = acc[mi][ni][r];
    __syncthreads();

    // reduce + pointwise: threads 0..255, one (batch, unit) each
    if (tid < 256) {
        float4 g4 = *(const float4*)&part[0][pb][pu * 4];
        #pragma unroll
        for (int w = 1; w < 8; ++w) {
            float4 p4 = *(const float4*)&part[w][pb][pu * 4];
            g4.x += p4.x; g4.y += p4.y; g4.z += p4.z; g4.w += p4.w;
        }
        const float vi = g4.x + ad.x, vf = g4.y + ad.y;
        const float vg = g4.z + ad.z, vo = g4.w + ad.w;
        float c = fsigmoid(vf) * creg + fsigmoid(vi) * ftanh(vg);
        float h = fsigmoid(vo) * ftanh(c);
        cs[si] = c;
        const unsigned short hb = f2bf(h);
        hout[si] = hb;
        if (layer == 0) y0bf[(long)tt * (BATCH * HDIM) + si] = hb;
        else            y1bf[(long)tt * (BATCH * HDIM) + si] = hb;
        if (tt == T_STEPS - 1) hf[layer * (BATCH * HDIM) + si] = h;
    }
}

// d_out tail: [h_f0 | h_f1 | c_f0 | c_f1], 16384 floats each
__global__ __launch_bounds__(256) void finalize_states(const float* __restrict__ hf,
                                                       const float* __restrict__ c0s,
                                                       const float* __restrict__ c1s,
                                                       float* __restrict__ out) {
    const int idx = blockIdx.x * 256 + threadIdx.x;   // 0..65535
    const long base = (long)MROWS * VOCAB;
    float v;
    if (idx < 32768)      v = hf[idx];
    else if (idx < 49152) v = c0s[idx - 32768];
    else                  v = c1s[idx - 49152];
    out[base + idx] = v;
}

// ---------------------------------------------------------------------------
extern "C" void kernel_launch(void* const* d_in, const int* in_sizes, int n_in,
                              void* d_out, int out_size, void* d_ws, size_t ws_size,
                              hipStream_t stream) {
    const int*   word  = (const int*)d_in[0];
    const int*   seq   = (const int*)d_in[1];
    const float* emb   = (const float*)d_in[2];
    const float* w2hW  = (const float*)d_in[3];
    const float* w2hb  = (const float*)d_in[4];
    const float* Wih0  = (const float*)d_in[5];
    const float* Whh0  = (const float*)d_in[6];
    const float* bih0  = (const float*)d_in[7];
    const float* bhh0  = (const float*)d_in[8];
    const float* Wih1  = (const float*)d_in[9];
    const float* Whh1  = (const float*)d_in[10];
    const float* bih1  = (const float*)d_in[11];
    const float* bhh1  = (const float*)d_in[12];
    const float* dec_W = (const float*)d_in[13];
    const float* dec_b = (const float*)d_in[14];
    float* out = (float*)d_out;

    char* ws = (char*)d_ws;
    size_t off = 0;
    float*          G0    = (float*)(ws + off);          off += (size_t)MROWS * GDIM * 4;   // 33.5 MB
    unsigned short* Xbf   = (unsigned short*)(ws + off); off += (size_t)MROWS * EDIM * 2;   //  4.2 MB
    unsigned short* Wih0p = (unsigned short*)(ws + off); off += (size_t)GDIM  * EDIM * 2;   //  2.1 MB
    unsigned short* Whh0p = (unsigned short*)(ws + off); off += (size_t)GDIM  * HDIM * 2;   //  2.1 MB
    unsigned short* Wih1p = (unsigned short*)(ws + off); off += (size_t)GDIM  * HDIM * 2;   //  2.1 MB
    unsigned short* Whh1p = (unsigned short*)(ws + off); off += (size_t)GDIM  * HDIM * 2;   //  2.1 MB
    unsigned short* decWb = (unsigned short*)(ws + off); off += (size_t)VPAD  * EDIM * 2;   // 51.2 MB
    unsigned short* y0bf  = (unsigned short*)(ws + off); off += (size_t)MROWS * HDIM * 2;   //  4.2 MB
    unsigned short* y1bf  = (unsigned short*)(ws + off); off += (size_t)MROWS * HDIM * 2;   //  4.2 MB
    float* b0p = (float*)(ws + off); off += (size_t)GDIM * 4;
    float* b1p = (float*)(ws + off); off += (size_t)GDIM * 4;
    unsigned short* h0A = (unsigned short*)(ws + off); off += (size_t)BATCH * HDIM * 2;
    unsigned short* h0B = (unsigned short*)(ws + off); off += (size_t)BATCH * HDIM * 2;
    unsigned short* h1A = (unsigned short*)(ws + off); off += (size_t)BATCH * HDIM * 2;
    unsigned short* h1B = (unsigned short*)(ws + off); off += (size_t)BATCH * HDIM * 2;
    float* c0s = (float*)(ws + off); off += (size_t)BATCH * HDIM * 4;
    float* c1s = (float*)(ws + off); off += (size_t)BATCH * HDIM * 4;
    float* hf  = (float*)(ws + off); off += (size_t)2 * BATCH * HDIM * 4;
    // total ~106 MB of d_ws

    // prologue (parallel)
    conv_decw<<<12512, 256, 0, stream>>>(dec_W, decWb);
    pack_conv<<<2048, 64, 0, stream>>>(Wih0, Wih0p);
    pack_conv<<<2048, 64, 0, stream>>>(Whh0, Whh0p);
    pack_conv<<<2048, 64, 0, stream>>>(Wih1, Wih1p);
    pack_conv<<<2048, 64, 0, stream>>>(Whh1, Whh1p);
    pack_bias<<<8, 256, 0, stream>>>(bih0, bhh0, bih1, bhh1, b0p, b1p);
    gather_x<<<2048, 256, 0, stream>>>(seq, emb, Xbf);
    init_c0<<<64, 256, 0, stream>>>(word, emb, w2hW, w2hb, c0s, c1s, h0A, h1A);

    // G0 = X @ Wih0p^T + b0p (packed gate order)   [4096 x 2048], K=512
    gemm_bt128<<<32 * 16, 256, 0, stream>>>(Xbf, Wih0p, G0, b0p, nullptr,
                                            512, GDIM, (long)GDIM, 16, 0);

    // skewed recurrence: layer0 step t || layer1 step t-1
    for (int t = 0; t <= T_STEPS; ++t)
        lstm_step2<<<128, 512, 0, stream>>>(G0, Whh0p, Wih1p, Whh1p, b1p,
                                            y0bf, y1bf, h0A, h0B, c0s,
                                            h1A, h1B, c1s, hf, t);

    // decoded = y1 @ dec_W^T + dec_b   [4096 x 50000], K=512
    // nontemporal C stores + n-major order (A stays L3-resident, B streamed once)
    gemm_bt128<<<32 * 391, 256, 0, stream>>>(y1bf, decWb, out, dec_b, nullptr,
                                             512, VOCAB, (long)VOCAB, 391, 3);

    finalize_states<<<256, 256, 0, stream>>>(hf, c0s, c1s, out);
}

// Round 7
// 1359.056 us; speedup vs baseline: 4.0544x; 1.1105x over previous
//
#include <hip/hip_runtime.h>
#include <hip/hip_bf16.h>
#include <cstdint>

// Problem dims
#define T_STEPS 128
#define BATCH   32
#define VOCAB   50000
#define EDIM    512
#define HDIM    512
#define GDIM    2048          // 4*H
#define MROWS   4096          // T*B
#define VPAD    50048         // 391 * 128 (padded N for decode GEMM)
#define BH      (BATCH * HDIM)

typedef short bf16x8 __attribute__((ext_vector_type(8)));
typedef float f32x4  __attribute__((ext_vector_type(4)));
typedef unsigned short us4 __attribute__((ext_vector_type(4)));
typedef unsigned short us8 __attribute__((ext_vector_type(8)));

#define MFMA16(a, b, c) __builtin_amdgcn_mfma_f32_16x16x32_bf16(a, b, c, 0, 0, 0)

// fast activations: __expf -> v_exp_f32 (native); division keeps full accuracy
__device__ __forceinline__ float fsigmoid(float x) {
    return 1.0f / (1.0f + __expf(-x));
}
__device__ __forceinline__ float ftanh(float x) {
    return 1.0f - 2.0f / (1.0f + __expf(2.0f * x));
}

// round-to-nearest-even fp32 -> bf16 bits
__device__ __forceinline__ unsigned short f2bf(float f) {
    unsigned int u = __float_as_uint(f);
    u = (u + 0x7fffu + ((u >> 16) & 1u)) >> 16;
    return (unsigned short)u;
}

// ---------------------------------------------------------------------------
// Prologue kernels
// ---------------------------------------------------------------------------

// dec_W [50000x512] fp32 -> [50048x512] bf16 with zero pad rows
__global__ __launch_bounds__(256) void conv_decw(const float* __restrict__ src,
                                                 unsigned short* __restrict__ dst) {
    long i = ((long)blockIdx.x * 256 + threadIdx.x) * 8;
    if (i >= (long)VPAD * EDIM) return;
    long row = i >> 9;
    us8 v;
    if (row < VOCAB) {
        float4 a = *(const float4*)(src + i);
        float4 b = *(const float4*)(src + i + 4);
        v[0] = f2bf(a.x); v[1] = f2bf(a.y); v[2] = f2bf(a.z); v[3] = f2bf(a.w);
        v[4] = f2bf(b.x); v[5] = f2bf(b.y); v[6] = f2bf(b.z); v[7] = f2bf(b.w);
    } else {
        v = (us8)0;
    }
    *(us8*)(dst + i) = v;
}

// Gate-interleaved pack+convert: dst[n'][k] = bf16(src[(n'&3)*512 + (n'>>2)][k])
__global__ __launch_bounds__(64) void pack_conv(const float* __restrict__ src,
                                                unsigned short* __restrict__ dst) {
    const int n = blockIdx.x;                       // packed row 0..2047
    const int orig = (n & 3) * 512 + (n >> 2);
    const int k = threadIdx.x * 8;
    const float* s = src + (long)orig * 512 + k;
    float4 a = *(const float4*)s;
    float4 b = *(const float4*)(s + 4);
    us8 v;
    v[0] = f2bf(a.x); v[1] = f2bf(a.y); v[2] = f2bf(a.z); v[3] = f2bf(a.w);
    v[4] = f2bf(b.x); v[5] = f2bf(b.y); v[6] = f2bf(b.z); v[7] = f2bf(b.w);
    *(us8*)(dst + (long)n * 512 + k) = v;
}

// packed bias sums
__global__ __launch_bounds__(256) void pack_bias(const float* __restrict__ bih0,
                                                 const float* __restrict__ bhh0,
                                                 const float* __restrict__ bih1,
                                                 const float* __restrict__ bhh1,
                                                 float* __restrict__ b0p,
                                                 float* __restrict__ b1p) {
    const int n = blockIdx.x * 256 + threadIdx.x;   // 0..2047
    const int orig = (n & 3) * 512 + (n >> 2);
    b0p[n] = bih0[orig] + bhh0[orig];
    b1p[n] = bih1[orig] + bhh1[orig];
}

// X[r, :] = bf16(emb[seq[r], :]) for r in [0, T*B)
__global__ __launch_bounds__(256) void gather_x(const int* __restrict__ seq,
                                                const float* __restrict__ emb,
                                                unsigned short* __restrict__ Xbf) {
    long i = ((long)blockIdx.x * 256 + threadIdx.x) * 4;
    if (i >= (long)MROWS * EDIM) return;
    int r   = (int)(i >> 9);
    int col = (int)(i & 511);
    const float* er = emb + (long)seq[r] * EDIM + col;
    float4 e = *(const float4*)er;
    us4 v;
    v[0] = f2bf(e.x); v[1] = f2bf(e.y); v[2] = f2bf(e.z); v[3] = f2bf(e.w);
    *(us4*)(Xbf + i) = v;
}

// c0[b,h] = emb[word[b]] . w2h_W[h] + w2h_b[h]; both layers start with c0.
// h0 = 0: zero slot 0 of y0bf/y1bf (h-state lives IN the y buffers).
__global__ __launch_bounds__(256) void init_c0(const int* __restrict__ word,
                                               const float* __restrict__ emb,
                                               const float* __restrict__ w2hW,
                                               const float* __restrict__ w2hb,
                                               float* __restrict__ c0s, float* __restrict__ c1s,
                                               unsigned short* __restrict__ y0bf,
                                               unsigned short* __restrict__ y1bf) {
    const int idx = blockIdx.x * 256 + threadIdx.x;   // 0..16383
    const int b = idx >> 9, hh = idx & 511;
    const float* er = emb + (long)word[b] * EDIM;
    const float* wr = w2hW + (long)hh * EDIM;
    float acc = w2hb[hh];
    #pragma unroll 4
    for (int k = 0; k < EDIM; k += 4) {
        float4 e4 = *(const float4*)(er + k);
        float4 w4 = *(const float4*)(wr + k);
        acc += e4.x * w4.x + e4.y * w4.y + e4.z * w4.z + e4.w * w4.w;
    }
    c0s[idx] = acc;
    c1s[idx] = acc;
    y0bf[idx] = 0;    // step-0 h slot
    y1bf[idx] = 0;
}

// ---------------------------------------------------------------------------
// MFMA GEMM: C[m,n] = sum_k A[m,k]*Bt[n,k] (+bias1[n] +bias2[n])
// Default n-fastest block order (R1-measured best: concurrent blocks share B
// panels and write a contiguous row band). Epilogue stages the C tile through
// LDS so stores are 512B-contiguous per wave (vs 64B scattered segments).
// ---------------------------------------------------------------------------
__global__ __launch_bounds__(256) void gemm_bt128(const unsigned short* __restrict__ A,
                                                  const unsigned short* __restrict__ Bt,
                                                  float* __restrict__ C,
                                                  const float* __restrict__ bias1,
                                                  const float* __restrict__ bias2,
                                                  int K, int Nreal, long ldc, int ntn) {
    __shared__ __align__(16) unsigned char smem[34048];   // As|Bs (32KB) / ctile (33.8KB)
    unsigned short* As = (unsigned short*)smem;
    unsigned short* Bs = (unsigned short*)(smem + 16384);
    float* ctile = (float*)smem;                          // [64][132] padded

    const int tid  = threadIdx.x;
    const long m0  = (long)(blockIdx.x / ntn) * 128;
    const long n0  = (long)(blockIdx.x % ntn) * 128;
    const int lane = tid & 63;
    const int wave = tid >> 6;
    const int wr = wave >> 1, wc = wave & 1;
    const int fr = lane & 15, fq = lane >> 4;

    f32x4 acc[4][4];
    #pragma unroll
    for (int i = 0; i < 4; ++i)
        #pragma unroll
        for (int j = 0; j < 4; ++j) acc[i][j] = (f32x4)0.0f;

    const int srow = tid >> 3;
    const int scol = (tid & 7) * 8;

    for (int kt = 0; kt < K; kt += 64) {
        #pragma unroll
        for (int i = 0; i < 4; ++i) {
            const unsigned short* ga = A  + (m0 + i * 32 + srow) * K + kt + scol;
            const unsigned short* gb = Bt + (n0 + i * 32 + srow) * K + kt + scol;
            __builtin_amdgcn_global_load_lds((const __attribute__((address_space(1))) void*)ga,
                                             (__attribute__((address_space(3))) void*)(As + i * 2048 + tid * 8),
                                             16, 0, 0);
            __builtin_amdgcn_global_load_lds((const __attribute__((address_space(1))) void*)gb,
                                             (__attribute__((address_space(3))) void*)(Bs + i * 2048 + tid * 8),
                                             16, 0, 0);
        }
        asm volatile("s_waitcnt vmcnt(0)" ::: "memory");
        __syncthreads();
        #pragma unroll
        for (int ks = 0; ks < 64; ks += 32) {
            bf16x8 af[4], bfr[4];
            #pragma unroll
            for (int mi = 0; mi < 4; ++mi)
                af[mi] = *(const bf16x8*)&As[(wr * 64 + mi * 16 + fr) * 64 + ks + fq * 8];
            #pragma unroll
            for (int ni = 0; ni < 4; ++ni)
                bfr[ni] = *(const bf16x8*)&Bs[(wc * 64 + ni * 16 + fr) * 64 + ks + fq * 8];
            #pragma unroll
            for (int mi = 0; mi < 4; ++mi)
                #pragma unroll
                for (int ni = 0; ni < 4; ++ni)
                    acc[mi][ni] = MFMA16(af[mi], bfr[ni], acc[mi][ni]);
        }
        __syncthreads();
    }

    // staged epilogue: two 64-row halves through LDS, 512B-contiguous stores
    #pragma unroll
    for (int h = 0; h < 2; ++h) {
        if (wr == h) {
            #pragma unroll
            for (int ni = 0; ni < 4; ++ni) {
                const long col = n0 + wc * 64 + ni * 16 + fr;
                float bs = 0.0f;
                if (col < Nreal)
                    bs = (bias1 ? bias1[col] : 0.0f) + (bias2 ? bias2[col] : 0.0f);
                #pragma unroll
                for (int mi = 0; mi < 4; ++mi)
                    #pragma unroll
                    for (int r = 0; r < 4; ++r)
                        ctile[(mi * 16 + fq * 4 + r) * 132 + wc * 64 + ni * 16 + fr] =
                            acc[mi][ni][r] + bs;
            }
        }
        __syncthreads();
        #pragma unroll
        for (int j = 0; j < 8; ++j) {
            const int flat = tid + j * 256;          // 0..2047 float4 units
            const int row = flat >> 5, colq = flat & 31;
            const long col4 = n0 + colq * 4;
            if (col4 < Nreal) {                      // Nreal % 4 == 0
                f32x4 v = *(const f32x4*)&ctile[row * 132 + colq * 4];
                *(f32x4*)&C[(m0 + h * 64 + row) * ldc + col4] = v;
            }
        }
        __syncthreads();
    }
}

// ---------------------------------------------------------------------------
// LSTM step, wave-level K-split (skewed): blocks 0..63 layer0 step t (32 packed
// cols each, 8 waves x K=64), blocks 64..127 layer1 step t-1 (32 cols, waves
// 0-3: y0@Wih1^T K=128 chunks, waves 4-7: h@Whh1^T K=128 chunks).
// h-state lives IN y0bf/y1bf (slot s holds h(s-1); slot 0 = zeros), so each
// pointwise thread does exactly one bf16 store. G0/bias/c prefetched into
// registers at entry. Kernel-launch boundary IS the cross-block barrier
// (R3: agent-scope flag sync costs ~39us/step vs ~7us/step for launches).
// ---------------------------------------------------------------------------
__global__ __launch_bounds__(512) void lstm_step2(
        const float* __restrict__ G0,              // [4096][2048] packed (b0p folded)
        const unsigned short* __restrict__ Whh0p,  // [2048][512] packed bf16
        const unsigned short* __restrict__ Wih1p,
        const unsigned short* __restrict__ Whh1p,
        const float* __restrict__ b1p,             // [2048] packed bias sum layer1
        unsigned short* __restrict__ y0bf,         // [T+1][32][512] bf16 (slot0=h init)
        unsigned short* __restrict__ y1bf,         // [T+1][32][512] bf16
        float* __restrict__ c0s, float* __restrict__ c1s,
        float* __restrict__ hf,                    // [2][32][512] fp32 final h
        int t) {
    __shared__ float part[8][32][32];              // 32 KB partial tiles
    int bid = blockIdx.x;
    const int tid  = threadIdx.x;
    const int wv   = tid >> 6, lane = tid & 63;
    const int fr   = lane & 15, fq = lane >> 4;

    int layer, tt, cg;
    if (bid < 64) { layer = 0; tt = t;     if (tt >= T_STEPS) return; cg = bid; }
    else          { layer = 1; tt = t - 1; if (tt < 0) return;       cg = bid - 64; }

    const unsigned short* hin;
    unsigned short* yout;
    float* cs;
    if (layer == 0) { hin = y0bf + (long)tt * BH; yout = y0bf + (long)(tt + 1) * BH; cs = c0s; }
    else            { hin = y1bf + (long)tt * BH; yout = y1bf + (long)(tt + 1) * BH; cs = c1s; }

    const int n_base = cg * 32;

    // ---- early prefetch of pointwise operands (hide latency under MFMA) ----
    const int pb = tid >> 3, pu = tid & 7;         // pointwise coords (tid<256)
    const int si = pb * HDIM + cg * 8 + pu;
    float creg = 0.0f;
    float4 ad = make_float4(0.f, 0.f, 0.f, 0.f);
    if (tid < 256) {
        creg = cs[si];
        if (layer == 0) ad = *(const float4*)(G0 + ((long)tt * BATCH + pb) * GDIM + n_base + pu * 4);
        else            ad = *(const float4*)(b1p + n_base + pu * 4);
    }

    f32x4 acc[2][2];
    acc[0][0] = (f32x4)0.0f; acc[0][1] = (f32x4)0.0f;
    acc[1][0] = (f32x4)0.0f; acc[1][1] = (f32x4)0.0f;

    if (layer == 0) {
        // waves 0..7, K chunk = 64 each, fully unrolled
        const int kbase = wv * 64;
        const unsigned short* A0 = hin + fr * 512 + kbase + fq * 8;
        const unsigned short* A1 = A0 + 16 * 512;
        const unsigned short* B0 = Whh0p + (long)(n_base + fr) * 512 + kbase + fq * 8;
        const unsigned short* B1 = B0 + 16 * 512;
        #pragma unroll
        for (int i = 0; i < 2; ++i) {
            bf16x8 a0 = *(const bf16x8*)(A0 + i * 32);
            bf16x8 a1 = *(const bf16x8*)(A1 + i * 32);
            bf16x8 b0 = *(const bf16x8*)(B0 + i * 32);
            bf16x8 b1 = *(const bf16x8*)(B1 + i * 32);
            acc[0][0] = MFMA16(a0, b0, acc[0][0]);
            acc[0][1] = MFMA16(a0, b1, acc[0][1]);
            acc[1][0] = MFMA16(a1, b0, acc[1][0]);
            acc[1][1] = MFMA16(a1, b1, acc[1][1]);
        }
    } else {
        // waves 0..3: y0[tt] @ Wih1^T ; waves 4..7: h1 @ Whh1^T ; K chunk = 128
        const unsigned short* Aop = (wv < 4) ? (y0bf + (long)(tt + 1) * BH) : hin;
        const unsigned short* Bop = (wv < 4) ? Wih1p : Whh1p;
        const int kbase = (wv & 3) * 128;
        const unsigned short* A0 = Aop + fr * 512 + kbase + fq * 8;
        const unsigned short* A1 = A0 + 16 * 512;
        const unsigned short* B0 = Bop + (long)(n_base + fr) * 512 + kbase + fq * 8;
        const unsigned short* B1 = B0 + 16 * 512;
        #pragma unroll
        for (int i = 0; i < 4; ++i) {
            bf16x8 a0 = *(const bf16x8*)(A0 + i * 32);
            bf16x8 a1 = *(const bf16x8*)(A1 + i * 32);
            bf16x8 b0 = *(const bf16x8*)(B0 + i * 32);
            bf16x8 b1 = *(const bf16x8*)(B1 + i * 32);
            acc[0][0] = MFMA16(a0, b0, acc[0][0]);
            acc[0][1] = MFMA16(a0, b1, acc[0][1]);
            acc[1][0] = MFMA16(a1, b0, acc[1][0]);
            acc[1][1] = MFMA16(a1, b1, acc[1][1]);
        }
    }

    // partial tiles -> LDS
    #pragma unroll
    for (int mi = 0; mi < 2; ++mi)
        #pragma unroll
        for (int ni = 0; ni < 2; ++ni)
            #pragma unroll
            for (int r = 0; r < 4; ++r)
                part[wv][mi * 16 + fq * 4 + r][ni * 16 + fr] = acc[mi][ni][r];
    __syncthreads();

    // reduce + pointwise: threads 0..255, one (batch, unit) each
    if (tid < 256) {
        float4 g4 = *(const float4*)&part[0][pb][pu * 4];
        #pragma unroll
        for (int w = 1; w < 8; ++w) {
            float4 p4 = *(const float4*)&part[w][pb][pu * 4];
            g4.x += p4.x; g4.y += p4.y; g4.z += p4.z; g4.w += p4.w;
        }
        const float vi = g4.x + ad.x, vf = g4.y + ad.y;
        const float vg = g4.z + ad.z, vo = g4.w + ad.w;
        float c = fsigmoid(vf) * creg + fsigmoid(vi) * ftanh(vg);
        float h = fsigmoid(vo) * ftanh(c);
        cs[si] = c;
        yout[si] = f2bf(h);
        if (tt == T_STEPS - 1) hf[layer * BH + si] = h;
    }
}

// d_out tail: [h_f0 | h_f1 | c_f0 | c_f1], 16384 floats each
__global__ __launch_bounds__(256) void finalize_states(const float* __restrict__ hf,
                                                       const float* __restrict__ c0s,
                                                       const float* __restrict__ c1s,
                                                       float* __restrict__ out) {
    const int idx = blockIdx.x * 256 + threadIdx.x;   // 0..65535
    const long base = (long)MROWS * VOCAB;
    float v;
    if (idx < 32768)      v = hf[idx];
    else if (idx < 49152) v = c0s[idx - 32768];
    else                  v = c1s[idx - 49152];
    out[base + idx] = v;
}

// ---------------------------------------------------------------------------
extern "C" void kernel_launch(void* const* d_in, const int* in_sizes, int n_in,
                              void* d_out, int out_size, void* d_ws, size_t ws_size,
                              hipStream_t stream) {
    const int*   word  = (const int*)d_in[0];
    const int*   seq   = (const int*)d_in[1];
    const float* emb   = (const float*)d_in[2];
    const float* w2hW  = (const float*)d_in[3];
    const float* w2hb  = (const float*)d_in[4];
    const float* Wih0  = (const float*)d_in[5];
    const float* Whh0  = (const float*)d_in[6];
    const float* bih0  = (const float*)d_in[7];
    const float* bhh0  = (const float*)d_in[8];
    const float* Wih1  = (const float*)d_in[9];
    const float* Whh1  = (const float*)d_in[10];
    const float* bih1  = (const float*)d_in[11];
    const float* bhh1  = (const float*)d_in[12];
    const float* dec_W = (const float*)d_in[13];
    const float* dec_b = (const float*)d_in[14];
    float* out = (float*)d_out;

    char* ws = (char*)d_ws;
    size_t off = 0;
    float*          G0    = (float*)(ws + off);          off += (size_t)MROWS * GDIM * 4;        // 33.5 MB
    unsigned short* Xbf   = (unsigned short*)(ws + off); off += (size_t)MROWS * EDIM * 2;        //  4.2 MB
    unsigned short* Wih0p = (unsigned short*)(ws + off); off += (size_t)GDIM  * EDIM * 2;        //  2.1 MB
    unsigned short* Whh0p = (unsigned short*)(ws + off); off += (size_t)GDIM  * HDIM * 2;        //  2.1 MB
    unsigned short* Wih1p = (unsigned short*)(ws + off); off += (size_t)GDIM  * HDIM * 2;        //  2.1 MB
    unsigned short* Whh1p = (unsigned short*)(ws + off); off += (size_t)GDIM  * HDIM * 2;        //  2.1 MB
    unsigned short* decWb = (unsigned short*)(ws + off); off += (size_t)VPAD  * EDIM * 2;        // 51.2 MB
    unsigned short* y0bf  = (unsigned short*)(ws + off); off += (size_t)(T_STEPS + 1) * BH * 2;  //  4.2 MB
    unsigned short* y1bf  = (unsigned short*)(ws + off); off += (size_t)(T_STEPS + 1) * BH * 2;  //  4.2 MB
    float* b0p = (float*)(ws + off); off += (size_t)GDIM * 4;
    float* b1p = (float*)(ws + off); off += (size_t)GDIM * 4;
    float* c0s = (float*)(ws + off); off += (size_t)BH * 4;
    float* c1s = (float*)(ws + off); off += (size_t)BH * 4;
    float* hf  = (float*)(ws + off); off += (size_t)2 * BH * 4;
    // total ~106 MB of d_ws

    // prologue (parallel)
    conv_decw<<<12512, 256, 0, stream>>>(dec_W, decWb);
    pack_conv<<<2048, 64, 0, stream>>>(Wih0, Wih0p);
    pack_conv<<<2048, 64, 0, stream>>>(Whh0, Whh0p);
    pack_conv<<<2048, 64, 0, stream>>>(Wih1, Wih1p);
    pack_conv<<<2048, 64, 0, stream>>>(Whh1, Whh1p);
    pack_bias<<<8, 256, 0, stream>>>(bih0, bhh0, bih1, bhh1, b0p, b1p);
    gather_x<<<2048, 256, 0, stream>>>(seq, emb, Xbf);
    init_c0<<<64, 256, 0, stream>>>(word, emb, w2hW, w2hb, c0s, c1s, y0bf, y1bf);

    // G0 = X @ Wih0p^T + b0p (packed gate order)   [4096 x 2048], K=512
    gemm_bt128<<<32 * 16, 256, 0, stream>>>(Xbf, Wih0p, G0, b0p, nullptr,
                                            512, GDIM, (long)GDIM, 16);

    // skewed recurrence: layer0 step t || layer1 step t-1
    for (int t = 0; t <= T_STEPS; ++t)
        lstm_step2<<<128, 512, 0, stream>>>(G0, Whh0p, Wih1p, Whh1p, b1p,
                                            y0bf, y1bf, c0s, c1s, hf, t);

    // decoded = y1 @ dec_W^T + dec_b   [4096 x 50000], K=512
    gemm_bt128<<<32 * 391, 256, 0, stream>>>(y1bf + BH, decWb, out, dec_b, nullptr,
                                             512, VOCAB, (long)VOCAB, 391);

    finalize_states<<<256, 256, 0, stream>>>(hf, c0s, c1s, out);
}